// Round 3
// baseline (571.774 us; speedup 1.0000x reference)
//
#include <hip/hip_runtime.h>
#include <hip/hip_bf16.h>
#include <math.h>

#define B_ 16
#define L_ 512
#define H_ 8
#define E_ 64

typedef float f32x4 __attribute__((ext_vector_type(4)));
typedef short bf16x8 __attribute__((ext_vector_type(8)));
typedef short s16x4 __attribute__((ext_vector_type(4)));
typedef unsigned int u32x4 __attribute__((ext_vector_type(4)));

__device__ __forceinline__ short f2bf(float f) {
    __hip_bfloat16 h = __float2bfloat16(f);
    return __builtin_bit_cast(short, h);
}

__device__ __forceinline__ bf16x8 cvt8(const float* p) {
    f32x4 a = *(const f32x4*)p;
    f32x4 b = *(const f32x4*)(p + 4);
    bf16x8 r;
    r[0] = f2bf(a[0]); r[1] = f2bf(a[1]); r[2] = f2bf(a[2]); r[3] = f2bf(a[3]);
    r[4] = f2bf(b[0]); r[5] = f2bf(b[1]); r[6] = f2bf(b[2]); r[7] = f2bf(b[3]);
    return r;
}

// ============ Prep 1: Q,K -> bf16 MFMA A/B fragment order ============
// dst[((bh*32 + tile)*2 + st)*512 + lane*8 + j] = src[b][tile*16+lm][h][st*32+g*8+j]
// lane = g*16+lm. Grid: 2(sel) * 128(bh) * 8(tile-grp) blocks, 256 thr (wave w -> tile).
__global__ void qk_prep(const float* __restrict__ Qg, const float* __restrict__ Kg,
                        unsigned short* __restrict__ Qf, unsigned short* __restrict__ Kf) {
    int bid = blockIdx.x;
    int tg = bid & 7, bh = (bid >> 3) & 127, sel = bid >> 10;
    const float* src = sel ? Kg : Qg;
    unsigned short* dst = sel ? Kf : Qf;
    int h = bh & 7, b = bh >> 3;
    int t = threadIdx.x;
    int w = t >> 6, l = t & 63, lm = l & 15, g = l >> 4;
    int tile = tg * 4 + w;
    int row = tile * 16 + lm;
    const float* p = src + ((size_t)(b * 512 + row) * 8 + h) * 64 + g * 8;
    unsigned short* d0 = dst + ((size_t)(bh * 32 + tile) * 2) * 512 + l * 8;
    bf16x8 v0 = cvt8(p);
    bf16x8 v1 = cvt8(p + 32);
    *(bf16x8*)d0        = v0;
    *(bf16x8*)(d0 + 512) = v1;
}

// ============ Prep 2: V -> bf16 V^T fragment order ============
// Vtf[((bh*4+dt)*16+ks)*512 + lane*8 + j] = V[b][ks*32+g*8+j][h][dt*16+lm]
// Grid: 128(bh) * 8(s-chunk) blocks, 256 thr (wave w -> dt).
__global__ void v_prep(const float* __restrict__ V, unsigned short* __restrict__ Vtf) {
    __shared__ float tile[64][68];
    int bid = blockIdx.x;
    int sc = bid & 7, bh = bid >> 3;
    int h = bh & 7, b = bh >> 3;
    int t = threadIdx.x;
    const float* vb = V + ((size_t)(b * 512 + sc * 64) * 8 + h) * 64;
    #pragma unroll
    for (int i = 0; i < 4; ++i) {
        int srow = i * 16 + (t >> 4);
        int d4 = (t & 15) * 4;
        f32x4 v = *(const f32x4*)(vb + (size_t)srow * 512 + d4);
        tile[srow][d4 + 0] = v[0]; tile[srow][d4 + 1] = v[1];
        tile[srow][d4 + 2] = v[2]; tile[srow][d4 + 3] = v[3];
    }
    __syncthreads();
    int dt = t >> 6, l = t & 63, lm = l & 15, g = l >> 4;
    #pragma unroll
    for (int ksl = 0; ksl < 2; ++ksl) {
        int ks = sc * 2 + ksl;
        bf16x8 u;
        #pragma unroll
        for (int j = 0; j < 8; ++j)
            u[j] = f2bf(tile[ksl * 32 + g * 8 + j][dt * 16 + lm]);
        *(bf16x8*)(Vtf + ((size_t)(bh * 4 + dt) * 16 + ks) * 512 + l * 8) = u;
    }
}

// ============ Fused attention + prior + sigma_full ============
// Block = 4 waves; wave owns 16 q-rows x 512 keys. Grid: 128 bh * 8 row-blocks.
__launch_bounds__(256, 2)
__global__ void attn_fused(const unsigned short* __restrict__ Qf,
                           const unsigned short* __restrict__ Kf,
                           const unsigned short* __restrict__ Vtf,
                           const float* __restrict__ sigma,
                           float* __restrict__ Vout,
                           float* __restrict__ series,
                           float* __restrict__ prior,
                           float* __restrict__ sigf) {
    __shared__ __align__(16) char lds[4 * 16384];
    int tid = threadIdx.x;
    int w = tid >> 6, l = tid & 63, lm = l & 15, g = l >> 4;

    int bid = blockIdx.x;
    int nid = (bid & 7) * 128 + (bid >> 3);    // XCD swizzle (bijective, 1024%8==0)
    int rb = nid & 7, bh = nid >> 3;
    int h = bh & 7, b = bh >> 3;
    int qt = rb * 4 + w;                        // wave's q-tile
    int l0 = qt * 16;                           // wave's q-row base

    char* wl = lds + w * 16384;                 // per-wave P tile [16][512] bf16, 1KB rows
    int swz = (lm & 7) << 4;

    // ---- Q fragments (coalesced 16B/lane) ----
    const unsigned short* qfp = Qf + ((size_t)(bh * 32 + qt) * 2) * 512 + l * 8;
    bf16x8 qf0 = *(const bf16x8*)qfp;
    bf16x8 qf1 = *(const bf16x8*)(qfp + 512);

    // ---- QK^T: acc[t] holds S^T[s=16t+4g+r][q=lm] (unscaled) ----
    const unsigned short* kfp = Kf + (size_t)bh * 32768 + l * 8;
    f32x4 acc[32];
    #pragma unroll
    for (int t = 0; t < 32; ++t) acc[t] = 0.0f;
    #pragma unroll
    for (int t = 0; t < 32; ++t) {
        bf16x8 k0 = *(const bf16x8*)(kfp + t * 1024);
        bf16x8 k1 = *(const bf16x8*)(kfp + t * 1024 + 512);
        acc[t] = __builtin_amdgcn_mfma_f32_16x16x32_bf16(k0, qf0, acc[t], 0, 0, 0);
        acc[t] = __builtin_amdgcn_mfma_f32_16x16x32_bf16(k1, qf1, acc[t], 0, 0, 0);
    }

    // ---- softmax over s (per lane: 128 values, all for q=lm) ----
    float m = -1e30f;
    #pragma unroll
    for (int t = 0; t < 32; ++t)
        m = fmaxf(m, fmaxf(fmaxf(acc[t][0], acc[t][1]), fmaxf(acc[t][2], acc[t][3])));
    m = fmaxf(m, __shfl_xor(m, 16));
    m = fmaxf(m, __shfl_xor(m, 32));
    const float SC = 0.125f * 1.44269504088896340736f;  // scale * log2(e)
    float ssum = 0.0f;
    #pragma unroll
    for (int t = 0; t < 32; ++t) {
        f32x4 p;
        #pragma unroll
        for (int r = 0; r < 4; ++r) {
            p[r] = exp2f((acc[t][r] - m) * SC);
            ssum += p[r];
        }
        acc[t] = p;
    }
    ssum += __shfl_xor(ssum, 16);
    ssum += __shfl_xor(ssum, 32);
    float inv = 1.0f / ssum;

    // ---- P -> LDS (bf16, unnormalized) + series stores straight from regs ----
    float* sp = series + ((size_t)bh * 512 + l0 + lm) * 512 + g * 4;
    #pragma unroll
    for (int t = 0; t < 32; ++t) {
        f32x4 p = acc[t];
        s16x4 pw;
        pw[0] = f2bf(p[0]); pw[1] = f2bf(p[1]); pw[2] = f2bf(p[2]); pw[3] = f2bf(p[3]);
        *(s16x4*)(wl + (((lm << 10) + 32 * t + 8 * g) ^ swz)) = pw;
        f32x4 sv; sv[0] = p[0] * inv; sv[1] = p[1] * inv; sv[2] = p[2] * inv; sv[3] = p[3] * inv;
        *(f32x4*)(sp + t * 16) = sv;
    }

    // ---- PV: O^T[d][q] += V^T[d][s] * P^T[s][q] ----
    f32x4 oacc[4];
    #pragma unroll
    for (int dt = 0; dt < 4; ++dt) oacc[dt] = 0.0f;
    const unsigned short* vfp = Vtf + (size_t)bh * 32768 + l * 8;
    #pragma unroll
    for (int ks = 0; ks < 16; ++ks) {
        bf16x8 pb = *(const bf16x8*)(wl + (((lm << 10) + 64 * ks + 16 * g) ^ swz));
        #pragma unroll
        for (int dt = 0; dt < 4; ++dt) {
            bf16x8 va = *(const bf16x8*)(vfp + (size_t)(dt * 16 + ks) * 512);
            oacc[dt] = __builtin_amdgcn_mfma_f32_16x16x32_bf16(va, pb, oacc[dt], 0, 0, 0);
        }
    }

    // ---- Vout via small LDS transpose (P region dead) ----
    float* Olds = (float*)wl;                   // [64 d][17 q]
    #pragma unroll
    for (int dt = 0; dt < 4; ++dt)
        #pragma unroll
        for (int r = 0; r < 4; ++r)
            Olds[(dt * 16 + g * 4 + r) * 17 + lm] = oacc[dt][r] * inv;
    #pragma unroll
    for (int it = 0; it < 4; ++it) {
        int rr = it * 4 + g;
        f32x4 o;
        #pragma unroll
        for (int e = 0; e < 4; ++e) o[e] = Olds[(lm * 4 + e) * 17 + rr];
        *(f32x4*)(Vout + ((size_t)(b * 512 + l0 + rr) * 8 + h) * 64 + lm * 4) = o;
    }

    // ---- prior + sigma_full for this block's 16 rows/wave ----
    int row_l = l0 + lm;                        // L-index of this lane's row
    float x = sigma[((size_t)b * 512 + row_l) * 8 + h];
    float s = 1.0f / (1.0f + exp2f(-7.2134752044448170368f * x)) + 1e-5f;
    float sg = exp2f(1.5849625007211562f * s) - 1.0f;
    float invc = 0.3989422804014327f / sg;
    float c2 = -0.72134752044448170368f / (sg * sg);
    size_t pbase = ((size_t)bh * 512 + row_l) * 512 + g * 128;
    f32x4 sgv; sgv[0] = sg; sgv[1] = sg; sgv[2] = sg; sgv[3] = sg;
    #pragma unroll
    for (int c4 = 0; c4 < 32; ++c4) {
        int j0 = g * 128 + c4 * 4;
        f32x4 pr;
        #pragma unroll
        for (int k = 0; k < 4; ++k) {
            float d = (float)(row_l - (j0 + k));
            pr[k] = invc * exp2f(c2 * d * d);
        }
        *(f32x4*)(prior + pbase + c4 * 4) = pr;
        *(f32x4*)(sigf + pbase + c4 * 4) = sgv;
    }
}

extern "C" void kernel_launch(void* const* d_in, const int* in_sizes, int n_in,
                              void* d_out, int out_size, void* d_ws, size_t ws_size,
                              hipStream_t stream) {
    const float* queries = (const float*)d_in[0];
    const float* keys    = (const float*)d_in[1];
    const float* values  = (const float*)d_in[2];
    const float* sigma   = (const float*)d_in[3];

    float* out = (float*)d_out;
    const size_t nV = (size_t)B_ * L_ * H_ * E_;     // 4,194,304
    const size_t nS = (size_t)B_ * H_ * L_ * L_;     // 33,554,432
    float* Vout       = out;
    float* series     = out + nV;
    float* prior      = out + nV + nS;
    float* sigma_full = out + nV + 2 * nS;

    // ws: bf16 fragment-packed Q, K, V^T (8.4 MB each)
    unsigned short* Qf  = (unsigned short*)d_ws;
    unsigned short* Kf  = Qf + nV;
    unsigned short* Vtf = Kf + nV;

    qk_prep<<<2048, 256, 0, stream>>>(queries, keys, Qf, Kf);
    v_prep<<<1024, 256, 0, stream>>>(values, Vtf);
    attn_fused<<<1024, 256, 0, stream>>>(Qf, Kf, Vtf, sigma,
                                         Vout, series, prior, sigma_full);
}

// Round 4
// 481.149 us; speedup vs baseline: 1.1884x; 1.1884x over previous
//
#include <hip/hip_runtime.h>
#include <hip/hip_bf16.h>
#include <math.h>

#define B_ 16
#define L_ 512
#define H_ 8
#define E_ 64

typedef float f32x4 __attribute__((ext_vector_type(4)));
typedef short bf16x8 __attribute__((ext_vector_type(8)));
typedef short s16x4 __attribute__((ext_vector_type(4)));

__device__ __forceinline__ short f2bf(float f) {
    __hip_bfloat16 h = __float2bfloat16(f);
    return __builtin_bit_cast(short, h);
}

__device__ __forceinline__ bf16x8 cvt8(const float* p) {
    f32x4 a = *(const f32x4*)p;
    f32x4 b = *(const f32x4*)(p + 4);
    bf16x8 r;
    r[0] = f2bf(a[0]); r[1] = f2bf(a[1]); r[2] = f2bf(a[2]); r[3] = f2bf(a[3]);
    r[4] = f2bf(b[0]); r[5] = f2bf(b[1]); r[6] = f2bf(b[2]); r[7] = f2bf(b[3]);
    return r;
}

// ============ sigma transform: sig_ws[B,H,L] = 3^(sigmoid(5x)+1e-5) - 1 ============
__global__ void sig_kernel(const float* __restrict__ sigma, float* __restrict__ sig_ws) {
    int o = blockIdx.x * 256 + threadIdx.x;   // over [B,H,L]
    int l = o & 511, bh = o >> 9;
    int h = bh & 7, b = bh >> 3;
    float x = sigma[((size_t)(b * 512 + l)) * 8 + h];
    float s = 1.0f / (1.0f + exp2f(-7.2134752044448170368f * x)) + 1e-5f;
    sig_ws[o] = exp2f(1.5849625007211562f * s) - 1.0f;
}

// ============ Prep 1: Q,K -> bf16 MFMA fragment order ============
__global__ void qk_prep(const float* __restrict__ Qg, const float* __restrict__ Kg,
                        unsigned short* __restrict__ Qf, unsigned short* __restrict__ Kf) {
    int bid = blockIdx.x;
    int tg = bid & 7, bh = (bid >> 3) & 127, sel = bid >> 10;
    const float* src = sel ? Kg : Qg;
    unsigned short* dst = sel ? Kf : Qf;
    int h = bh & 7, b = bh >> 3;
    int t = threadIdx.x;
    int w = t >> 6, l = t & 63, lm = l & 15, g = l >> 4;
    int tile = tg * 4 + w;
    int row = tile * 16 + lm;
    const float* p = src + ((size_t)(b * 512 + row) * 8 + h) * 64 + g * 8;
    unsigned short* d0 = dst + ((size_t)(bh * 32 + tile) * 2) * 512 + l * 8;
    *(bf16x8*)d0         = cvt8(p);
    *(bf16x8*)(d0 + 512) = cvt8(p + 32);
}

// ============ Prep 2: V -> bf16 V^T fragment order ============
__global__ void v_prep(const float* __restrict__ V, unsigned short* __restrict__ Vtf) {
    __shared__ float tile[64][67];            // stride 67: 8*67 % 32 != 0 -> no 4-way conflict
    int bid = blockIdx.x;
    int sc = bid & 7, bh = bid >> 3;
    int h = bh & 7, b = bh >> 3;
    int t = threadIdx.x;
    const float* vb = V + ((size_t)(b * 512 + sc * 64) * 8 + h) * 64;
    #pragma unroll
    for (int i = 0; i < 4; ++i) {
        int srow = i * 16 + (t >> 4);
        int d4 = (t & 15) * 4;
        f32x4 v = *(const f32x4*)(vb + (size_t)srow * 512 + d4);
        tile[srow][d4 + 0] = v[0]; tile[srow][d4 + 1] = v[1];
        tile[srow][d4 + 2] = v[2]; tile[srow][d4 + 3] = v[3];
    }
    __syncthreads();
    int dt = t >> 6, l = t & 63, lm = l & 15, g = l >> 4;
    #pragma unroll
    for (int ksl = 0; ksl < 2; ++ksl) {
        int ks = sc * 2 + ksl;
        bf16x8 u;
        #pragma unroll
        for (int j = 0; j < 8; ++j)
            u[j] = f2bf(tile[ksl * 32 + g * 8 + j][dt * 16 + lm]);
        *(bf16x8*)(Vtf + ((size_t)(bh * 4 + dt) * 16 + ks) * 512 + l * 8) = u;
    }
}

// ============ MFMA attention: series + Vout ============
__launch_bounds__(256, 2)
__global__ void attn_kernel(const unsigned short* __restrict__ Qf,
                            const unsigned short* __restrict__ Kf,
                            const unsigned short* __restrict__ Vtf,
                            float* __restrict__ Vout,
                            float* __restrict__ series) {
    __shared__ __align__(16) char lds[4 * 16384];
    int tid = threadIdx.x;
    int w = tid >> 6, l = tid & 63, lm = l & 15, g = l >> 4;

    int bid = blockIdx.x;
    int nid = (bid & 7) * 128 + (bid >> 3);   // XCD swizzle (bijective, 1024 % 8 == 0)
    int rb = nid & 7, bh = nid >> 3;
    int h = bh & 7, b = bh >> 3;
    int qt = rb * 4 + w;
    int l0 = qt * 16;

    char* wl = lds + w * 16384;               // per-wave P tile [16][512] bf16
    int swz = (lm & 7) << 4;

    const unsigned short* qfp = Qf + ((size_t)(bh * 32 + qt) * 2) * 512 + l * 8;
    bf16x8 qf0 = *(const bf16x8*)qfp;
    bf16x8 qf1 = *(const bf16x8*)(qfp + 512);

    // QK^T: acc[t] = S^T[s=16t+4g+r][q=lm]
    const unsigned short* kfp = Kf + (size_t)bh * 32768 + l * 8;
    f32x4 acc[32];
    #pragma unroll
    for (int t = 0; t < 32; ++t) acc[t] = 0.0f;
    #pragma unroll
    for (int t = 0; t < 32; ++t) {
        bf16x8 k0 = *(const bf16x8*)(kfp + t * 1024);
        bf16x8 k1 = *(const bf16x8*)(kfp + t * 1024 + 512);
        acc[t] = __builtin_amdgcn_mfma_f32_16x16x32_bf16(k0, qf0, acc[t], 0, 0, 0);
        acc[t] = __builtin_amdgcn_mfma_f32_16x16x32_bf16(k1, qf1, acc[t], 0, 0, 0);
    }

    // softmax over s (per lane: 128 values for q=lm)
    float m = -1e30f;
    #pragma unroll
    for (int t = 0; t < 32; ++t)
        m = fmaxf(m, fmaxf(fmaxf(acc[t][0], acc[t][1]), fmaxf(acc[t][2], acc[t][3])));
    m = fmaxf(m, __shfl_xor(m, 16));
    m = fmaxf(m, __shfl_xor(m, 32));
    const float SC = 0.125f * 1.44269504088896340736f;
    float ssum = 0.0f;
    #pragma unroll
    for (int t = 0; t < 32; ++t) {
        f32x4 p;
        #pragma unroll
        for (int r = 0; r < 4; ++r) {
            p[r] = exp2f((acc[t][r] - m) * SC);
            ssum += p[r];
        }
        acc[t] = p;
    }
    ssum += __shfl_xor(ssum, 16);
    ssum += __shfl_xor(ssum, 32);
    float inv = 1.0f / ssum;

    // P -> per-wave LDS (bf16) + series straight from regs (16 rows x 64B lines/inst)
    float* sp = series + ((size_t)bh * 512 + l0 + lm) * 512 + g * 4;
    #pragma unroll
    for (int t = 0; t < 32; ++t) {
        f32x4 p = acc[t];
        s16x4 pw;
        pw[0] = f2bf(p[0]); pw[1] = f2bf(p[1]); pw[2] = f2bf(p[2]); pw[3] = f2bf(p[3]);
        *(s16x4*)(wl + (((lm << 10) + 32 * t + 8 * g) ^ swz)) = pw;
        f32x4 sv; sv[0] = p[0] * inv; sv[1] = p[1] * inv; sv[2] = p[2] * inv; sv[3] = p[3] * inv;
        *(f32x4*)(sp + t * 16) = sv;
    }

    // PV: O^T[d][q] += V^T[d][s] * P^T[s][q]
    f32x4 oacc[4];
    #pragma unroll
    for (int dt = 0; dt < 4; ++dt) oacc[dt] = 0.0f;
    const unsigned short* vfp = Vtf + (size_t)bh * 32768 + l * 8;
    #pragma unroll
    for (int ks = 0; ks < 16; ++ks) {
        bf16x8 pb = *(const bf16x8*)(wl + (((lm << 10) + 64 * ks + 16 * g) ^ swz));
        #pragma unroll
        for (int dt = 0; dt < 4; ++dt) {
            bf16x8 va = *(const bf16x8*)(vfp + (size_t)(dt * 16 + ks) * 512);
            oacc[dt] = __builtin_amdgcn_mfma_f32_16x16x32_bf16(va, pb, oacc[dt], 0, 0, 0);
        }
    }

    // Vout via small LDS transpose (P region dead)
    float* Olds = (float*)wl;                 // [64 d][17 q]
    #pragma unroll
    for (int dt = 0; dt < 4; ++dt)
        #pragma unroll
        for (int r = 0; r < 4; ++r)
            Olds[(dt * 16 + g * 4 + r) * 17 + lm] = oacc[dt][r] * inv;
    #pragma unroll
    for (int it = 0; it < 4; ++it) {
        int rr = it * 4 + g;
        f32x4 o;
        #pragma unroll
        for (int e = 0; e < 4; ++e) o[e] = Olds[(lm * 4 + e) * 17 + rr];
        *(f32x4*)(Vout + ((size_t)(b * 512 + l0 + rr) * 8 + h) * 64 + lm * 4) = o;
    }
}

// ============ prior + sigma_full: fully-coalesced row-cooperative stores ============
// Per wave: 4 rows; per row, lane l owns cols {l*4, 256+l*4} -> every store inst
// is 64 lanes x 16B contiguous = 1KB. Grid 4096 x 256 thr.
__launch_bounds__(256)
__global__ void prior_kernel2(const float* __restrict__ sig_ws,
                              float* __restrict__ prior,
                              float* __restrict__ sigf) {
    int t = threadIdx.x;
    int w = t >> 6, l = t & 63;
    int row0 = blockIdx.x * 16 + w * 4;       // over [B*H*L]
    #pragma unroll
    for (int r = 0; r < 4; ++r) {
        int row = row0 + r;
        int row_l = row & 511;
        float sg = sig_ws[row];
        float invc = 0.3989422804014327f / sg;
        float c2 = -0.72134752044448170368f / (sg * sg);  // -log2(e)/(2 sg^2)
        size_t base = (size_t)row * 512;
        f32x4 sgv; sgv[0] = sg; sgv[1] = sg; sgv[2] = sg; sgv[3] = sg;
        #pragma unroll
        for (int j = 0; j < 2; ++j) {
            int c0 = j * 256 + l * 4;
            f32x4 pr;
            #pragma unroll
            for (int k = 0; k < 4; ++k) {
                float d = (float)(row_l - (c0 + k));
                pr[k] = invc * exp2f(c2 * d * d);
            }
            *(f32x4*)(prior + base + c0) = pr;
            *(f32x4*)(sigf + base + c0) = sgv;
        }
    }
}

extern "C" void kernel_launch(void* const* d_in, const int* in_sizes, int n_in,
                              void* d_out, int out_size, void* d_ws, size_t ws_size,
                              hipStream_t stream) {
    const float* queries = (const float*)d_in[0];
    const float* keys    = (const float*)d_in[1];
    const float* values  = (const float*)d_in[2];
    const float* sigma   = (const float*)d_in[3];

    float* out = (float*)d_out;
    const size_t nV = (size_t)B_ * L_ * H_ * E_;     // 4,194,304
    const size_t nS = (size_t)B_ * H_ * L_ * L_;     // 33,554,432
    float* Vout       = out;
    float* series     = out + nV;
    float* prior      = out + nV + nS;
    float* sigma_full = out + nV + 2 * nS;

    unsigned short* Qf  = (unsigned short*)d_ws;     // 8.4 MB each
    unsigned short* Kf  = Qf + nV;
    unsigned short* Vtf = Kf + nV;
    float* sig_ws = (float*)(Vtf + nV);              // 256 KB

    sig_kernel<<<B_ * H_ * L_ / 256, 256, 0, stream>>>(sigma, sig_ws);
    qk_prep<<<2048, 256, 0, stream>>>(queries, keys, Qf, Kf);
    v_prep<<<1024, 256, 0, stream>>>(values, Vtf);
    attn_kernel<<<1024, 256, 0, stream>>>(Qf, Kf, Vtf, Vout, series);
    prior_kernel2<<<4096, 256, 0, stream>>>(sig_ws, prior, sigma_full);
}